// Round 10
// baseline (286.200 us; speedup 1.0000x reference)
//
#include <hip/hip_runtime.h>

using u16 = unsigned short;
using u32 = unsigned int;

// Problem constants (from reference)
constexpr int Nn  = 50000;   // nodes
constexpr int Ee  = 800000;  // edges
constexpr int Bb  = 256;     // graphs
constexpr int INF = 32;      // input feature dim
constexpr int Hh  = 96;      // hidden dim
constexpr float BN_EPS = 1e-5f;

// Binned CSR build parameters
constexpr int BINW = 256;                      // nodes per bin
constexpr int NBIN = (Nn + BINW - 1) / BINW;   // 196
constexpr int P1B  = 256;                      // pass-1 blocks
constexpr int EPB  = Ee / P1B;                 // 3125 edges per block (exact)
constexpr int CAP  = 64;                       // per (block,bin) capacity (mean 16, 12 sigma)

// ---------------- bf16 helpers (rne) ----------------
__device__ __forceinline__ float bfL(u32 u) { return __uint_as_float(u << 16); }
__device__ __forceinline__ float bfH(u32 u) { return __uint_as_float(u & 0xFFFF0000u); }
__device__ __forceinline__ u32 f2bfb(float f) {            // rounded bf16 bits (low 16)
    u32 b = __float_as_uint(f);
    return (b + 0x7FFFu + ((b >> 16) & 1u)) >> 16;
}
__device__ __forceinline__ float bf2f(u16 u) { return __uint_as_float(((u32)u) << 16); }

// ---------------------------------------------------------------------------
// x -> bf16 table (N x 32)
// ---------------------------------------------------------------------------
__global__ void x2bf_kernel(const float* __restrict__ x, u16* __restrict__ xb) {
    const int total = Nn * INF / 8;
    for (int i = blockIdx.x * 256 + threadIdx.x; i < total; i += gridDim.x * 256) {
        const float4 a = ((const float4*)x)[2 * i];
        const float4 b = ((const float4*)x)[2 * i + 1];
        uint4 R;
        R.x = f2bfb(a.x) | (f2bfb(a.y) << 16);
        R.y = f2bfb(a.z) | (f2bfb(a.w) << 16);
        R.z = f2bfb(b.x) | (f2bfb(b.y) << 16);
        R.w = f2bfb(b.z) | (f2bfb(b.w) << 16);
        ((uint4*)xb)[i] = R;
    }
}

// ---------------------------------------------------------------------------
// CSR build pass 1: bin edges into per-(block,bin) private regions.
// ---------------------------------------------------------------------------
__global__ __launch_bounds__(256)
void p1_bin_kernel(const int* __restrict__ src, const int* __restrict__ dst,
                   u32* __restrict__ binbuf, int* __restrict__ counts) {
    __shared__ int cur[NBIN];
    const int b = blockIdx.x, tid = threadIdx.x;
    for (int k = tid; k < NBIN; k += 256) cur[k] = 0;
    __syncthreads();
    const long e0 = (long)b * EPB;
    for (int i = tid; i < EPB; i += 256) {
        const long e = e0 + i;
        const int d = dst[e];
        const int k = d >> 8;
        const int pos = atomicAdd(&cur[k], 1);
        binbuf[((long)b * NBIN + k) * CAP + pos] = ((u32)(d & 255) << 16) | (u32)src[e];
    }
    __syncthreads();
    for (int k = tid; k < NBIN; k += 256) counts[k * P1B + b] = cur[k];
}

// ---------------------------------------------------------------------------
// CSR build pass 2: bin totals -> exclusive prefix (binbase); rowptr[N] = E.
// ---------------------------------------------------------------------------
__global__ void p2_binscan_kernel(const int* __restrict__ counts, int* __restrict__ binbase,
                                  int* __restrict__ rowptr) {
    __shared__ int ps[256];
    const int t = threadIdx.x;
    int tot = 0;
    if (t < NBIN) {
        const int* cp = counts + t * P1B;
        for (int b = 0; b < P1B; ++b) tot += cp[b];
    }
    ps[t] = tot;
    __syncthreads();
    for (int d = 1; d < 256; d <<= 1) {
        int u = (t >= d) ? ps[t - d] : 0;
        __syncthreads();
        if (t >= d) ps[t] += u;
        __syncthreads();
    }
    if (t < NBIN) binbase[t] = ps[t] - tot;   // exclusive prefix
    if (t == 0) rowptr[Nn] = Ee;
}

// ---------------------------------------------------------------------------
// CSR build pass 3: one block per bin -> rowptr slice + sorted u16 csr window.
// ---------------------------------------------------------------------------
__global__ __launch_bounds__(256)
void p3_binsort_kernel(const u32* __restrict__ binbuf, const int* __restrict__ counts,
                       const int* __restrict__ binbase, int* __restrict__ rowptr,
                       u16* __restrict__ csr) {
    __shared__ int cnt[P1B];
    __shared__ int lhist[BINW];
    __shared__ int lpref[BINW];
    const int k = blockIdx.x, tid = threadIdx.x;

    for (int b = tid; b < P1B; b += 256) cnt[b] = counts[k * P1B + b];
    lhist[tid] = 0;
    __syncthreads();

    for (int flat = tid; flat < P1B * CAP; flat += 256) {
        const int b = flat / CAP, i = flat % CAP;
        if (i < cnt[b])
            atomicAdd(&lhist[binbuf[((long)b * NBIN + k) * CAP + i] >> 16], 1);
    }
    __syncthreads();

    const int v = lhist[tid];
    lpref[tid] = v;
    __syncthreads();
    for (int d = 1; d < 256; d <<= 1) {
        int u = (tid >= d) ? lpref[tid - d] : 0;
        __syncthreads();
        if (tid >= d) lpref[tid] += u;
        __syncthreads();
    }
    lpref[tid] -= v;

    const int base = binbase[k];
    const int node = k * BINW + tid;
    if (node < Nn) rowptr[node] = base + lpref[tid];
    lhist[tid] = 0;                         // reuse as cursor
    __syncthreads();

    for (int flat = tid; flat < P1B * CAP; flat += 256) {
        const int b = flat / CAP, i = flat % CAP;
        if (i < cnt[b]) {
            const u32 pv = binbuf[((long)b * NBIN + k) * CAP + i];
            const int dl = pv >> 16;
            const int pos = base + lpref[dl] + atomicAdd(&lhist[dl], 1);
            csr[pos] = (u16)(pv & 0xFFFFu);
        }
    }
}

// ---------------------------------------------------------------------------
// FUSED agg + FC1 + BN + ReLU.
// Gather: 4 threads/node, 3x-unrolled edge loop (9 uint4 in flight), bf16
// deposit into LDS x-tile. Weights staged in LDS as bf16 (halves LDS ->
// 5 blocks/CU). GEMM consumes k-pairs.
// ---------------------------------------------------------------------------
template<int DIN>
__global__ __launch_bounds__(256, 5)
void fused_agg_fc1_kernel(const u16* __restrict__ hsrc, const int* __restrict__ rowptr,
                          const u16* __restrict__ csr, const float* __restrict__ w,
                          const float* __restrict__ b_in,
                          const float* __restrict__ gamma, const float* __restrict__ beta,
                          const float* __restrict__ rmean, const float* __restrict__ rvar,
                          u16* __restrict__ out) {
    constexpr int RU4  = DIN / 8;             // uint4 per row (4 or 12)
    constexpr int S    = RU4 / 4;             // row slots per thread (1 or 3)
    constexpr int XSTU = DIN + 2;             // u16 stride (34 or 98)
    __shared__ u16 wb[DIN * Hh];              // bf16 weights
    __shared__ u16 xs[64 * XSTU];             // bf16 x tile

    const int tid = threadIdx.x;
    const int nbase = blockIdx.x * 64;

    // stage weights [DIN x 96] fp32 -> bf16
    for (int i = tid * 4; i < DIN * Hh; i += 1024) {
        const float4 v = *(const float4*)&w[i];
        u32* p = (u32*)&wb[i];
        p[0] = f2bfb(v.x) | (f2bfb(v.y) << 16);
        p[1] = f2bfb(v.z) | (f2bfb(v.w) << 16);
    }

    // gather: node = nbase + (tid>>2), lane ln covers columns [(s*4+ln)*8, +8)
    {
        const int grp = tid >> 2, ln = tid & 3;
        const int node = nbase + grp;
        if (node < Nn) {
            const uint4* h4 = (const uint4*)hsrc;
            float a[S][8];
            #pragma unroll
            for (int s = 0; s < S; ++s) {
                const uint4 U = h4[(long)node * RU4 + s * 4 + ln];
                a[s][0] = bfL(U.x); a[s][1] = bfH(U.x); a[s][2] = bfL(U.y); a[s][3] = bfH(U.y);
                a[s][4] = bfL(U.z); a[s][5] = bfH(U.z); a[s][6] = bfL(U.w); a[s][7] = bfH(U.w);
            }
            const int e0 = rowptr[node], e1 = rowptr[node + 1];
            int e = e0;
            for (; e + 3 <= e1; e += 3) {                  // 3x unroll: 3S loads in flight
                const long s0 = csr[e], s1 = csr[e + 1], s2 = csr[e + 2];
                uint4 U0[S], U1[S], U2[S];
                #pragma unroll
                for (int s = 0; s < S; ++s) U0[s] = h4[s0 * RU4 + s * 4 + ln];
                #pragma unroll
                for (int s = 0; s < S; ++s) U1[s] = h4[s1 * RU4 + s * 4 + ln];
                #pragma unroll
                for (int s = 0; s < S; ++s) U2[s] = h4[s2 * RU4 + s * 4 + ln];
                #pragma unroll
                for (int s = 0; s < S; ++s) {
                    a[s][0] += bfL(U0[s].x); a[s][1] += bfH(U0[s].x);
                    a[s][2] += bfL(U0[s].y); a[s][3] += bfH(U0[s].y);
                    a[s][4] += bfL(U0[s].z); a[s][5] += bfH(U0[s].z);
                    a[s][6] += bfL(U0[s].w); a[s][7] += bfH(U0[s].w);
                    a[s][0] += bfL(U1[s].x); a[s][1] += bfH(U1[s].x);
                    a[s][2] += bfL(U1[s].y); a[s][3] += bfH(U1[s].y);
                    a[s][4] += bfL(U1[s].z); a[s][5] += bfH(U1[s].z);
                    a[s][6] += bfL(U1[s].w); a[s][7] += bfH(U1[s].w);
                    a[s][0] += bfL(U2[s].x); a[s][1] += bfH(U2[s].x);
                    a[s][2] += bfL(U2[s].y); a[s][3] += bfH(U2[s].y);
                    a[s][4] += bfL(U2[s].z); a[s][5] += bfH(U2[s].z);
                    a[s][6] += bfL(U2[s].w); a[s][7] += bfH(U2[s].w);
                }
            }
            for (; e < e1; ++e) {
                const long s0 = csr[e];
                #pragma unroll
                for (int s = 0; s < S; ++s) {
                    const uint4 U = h4[s0 * RU4 + s * 4 + ln];
                    a[s][0] += bfL(U.x); a[s][1] += bfH(U.x);
                    a[s][2] += bfL(U.y); a[s][3] += bfH(U.y);
                    a[s][4] += bfL(U.z); a[s][5] += bfH(U.z);
                    a[s][6] += bfL(U.w); a[s][7] += bfH(U.w);
                }
            }
            #pragma unroll
            for (int s = 0; s < S; ++s) {
                u32* xp = (u32*)&xs[grp * XSTU + (s * 4 + ln) * 8];
                #pragma unroll
                for (int q = 0; q < 4; ++q)
                    xp[q] = f2bfb(a[s][2 * q]) | (f2bfb(a[s][2 * q + 1]) << 16);
            }
        }
    }

    // BN epilogue constants
    const int jt = tid & 15, nt = tid >> 4;
    const int j0 = jt * 6;
    float A[6], C[6];
    #pragma unroll
    for (int ji = 0; ji < 6; ++ji) {
        const int j = j0 + ji;
        const float s = gamma[j] * rsqrtf(rvar[j] + BN_EPS);
        A[ji] = s;
        C[ji] = (b_in[j] - rmean[j]) * s + beta[j];
    }
    __syncthreads();

    float acc[4][6] = {};
    #pragma unroll 2
    for (int k2 = 0; k2 < DIN / 2; ++k2) {
        float xlo[4], xhi[4];
        #pragma unroll
        for (int ni = 0; ni < 4; ++ni) {
            const u32 xv = *(const u32*)&xs[(nt * 4 + ni) * XSTU + k2 * 2];
            xlo[ni] = bfL(xv); xhi[ni] = bfH(xv);
        }
        float wlo[6], whi[6];
        #pragma unroll
        for (int q = 0; q < 3; ++q) {
            const u32 w0 = *(const u32*)&wb[(2 * k2)     * Hh + j0 + 2 * q];
            const u32 w1 = *(const u32*)&wb[(2 * k2 + 1) * Hh + j0 + 2 * q];
            wlo[2 * q] = bfL(w0); wlo[2 * q + 1] = bfH(w0);
            whi[2 * q] = bfL(w1); whi[2 * q + 1] = bfH(w1);
        }
        #pragma unroll
        for (int ni = 0; ni < 4; ++ni)
            #pragma unroll
            for (int ji = 0; ji < 6; ++ji) {
                acc[ni][ji] = fmaf(xlo[ni], wlo[ji], acc[ni][ji]);
                acc[ni][ji] = fmaf(xhi[ni], whi[ji], acc[ni][ji]);
            }
    }

    #pragma unroll
    for (int ni = 0; ni < 4; ++ni) {
        const int node = nbase + nt * 4 + ni;
        if (node < Nn) {
            u16* op = out + (long)node * Hh + j0;
            #pragma unroll
            for (int q = 0; q < 3; ++q) {
                const float r0 = fmaxf(fmaf(acc[ni][2 * q],     A[2 * q],     C[2 * q]),     0.0f);
                const float r1 = fmaxf(fmaf(acc[ni][2 * q + 1], A[2 * q + 1], C[2 * q + 1]), 0.0f);
                *(u32*)(op + 2 * q) = f2bfb(r0) | (f2bfb(r1) << 16);
            }
        }
    }
}

// ---------------------------------------------------------------------------
// FC2 + ReLU (bf16 in/out), register-blocked, bf16 LDS for both x and w.
// ---------------------------------------------------------------------------
__global__ __launch_bounds__(256, 5)
void fc2_kernel(const u16* __restrict__ xin, const float* __restrict__ w,
                const float* __restrict__ b_out, u16* __restrict__ out) {
    constexpr int DIN  = Hh;
    constexpr int XSTU = DIN + 2;             // 98
    __shared__ u16 wb[DIN * Hh];
    __shared__ u16 xs[64 * XSTU];

    const int tid = threadIdx.x;
    const int jt  = tid & 15;
    const int nt  = tid >> 4;
    const int j0  = jt * 6;
    const int nbase = blockIdx.x * 64;

    for (int i = tid * 4; i < DIN * Hh; i += 1024) {
        const float4 v = *(const float4*)&w[i];
        u32* p = (u32*)&wb[i];
        p[0] = f2bfb(v.x) | (f2bfb(v.y) << 16);
        p[1] = f2bfb(v.z) | (f2bfb(v.w) << 16);
    }

    // stage x tile raw bf16
    for (int idx = tid; idx < 64 * (DIN / 8); idx += 256) {
        const int r = idx / (DIN / 8), c = idx % (DIN / 8);
        const int gr = nbase + r;
        uint4 U = make_uint4(0u, 0u, 0u, 0u);
        if (gr < Nn) U = ((const uint4*)(xin + (long)gr * DIN))[c];
        u32* xp = (u32*)&xs[r * XSTU + c * 8];
        xp[0] = U.x; xp[1] = U.y; xp[2] = U.z; xp[3] = U.w;
    }

    float C[6];
    #pragma unroll
    for (int ji = 0; ji < 6; ++ji) C[ji] = b_out[j0 + ji];
    __syncthreads();

    float acc[4][6] = {};
    #pragma unroll 2
    for (int k2 = 0; k2 < DIN / 2; ++k2) {
        float xlo[4], xhi[4];
        #pragma unroll
        for (int ni = 0; ni < 4; ++ni) {
            const u32 xv = *(const u32*)&xs[(nt * 4 + ni) * XSTU + k2 * 2];
            xlo[ni] = bfL(xv); xhi[ni] = bfH(xv);
        }
        float wlo[6], whi[6];
        #pragma unroll
        for (int q = 0; q < 3; ++q) {
            const u32 w0 = *(const u32*)&wb[(2 * k2)     * Hh + j0 + 2 * q];
            const u32 w1 = *(const u32*)&wb[(2 * k2 + 1) * Hh + j0 + 2 * q];
            wlo[2 * q] = bfL(w0); wlo[2 * q + 1] = bfH(w0);
            whi[2 * q] = bfL(w1); whi[2 * q + 1] = bfH(w1);
        }
        #pragma unroll
        for (int ni = 0; ni < 4; ++ni)
            #pragma unroll
            for (int ji = 0; ji < 6; ++ji) {
                acc[ni][ji] = fmaf(xlo[ni], wlo[ji], acc[ni][ji]);
                acc[ni][ji] = fmaf(xhi[ni], whi[ji], acc[ni][ji]);
            }
    }

    #pragma unroll
    for (int ni = 0; ni < 4; ++ni) {
        const int node = nbase + nt * 4 + ni;
        if (node < Nn) {
            u16* op = out + (long)node * Hh + j0;
            #pragma unroll
            for (int q = 0; q < 3; ++q) {
                const float r0 = fmaxf(acc[ni][2 * q]     + C[2 * q],     0.0f);
                const float r1 = fmaxf(acc[ni][2 * q + 1] + C[2 * q + 1], 0.0f);
                *(u32*)(op + 2 * q) = f2bfb(r0) | (f2bfb(r1) << 16);
            }
        }
    }
}

// ---------------------------------------------------------------------------
// Chunked pooling over bf16 table (batch sorted; boundary-flush atomics)
// ---------------------------------------------------------------------------
constexpr int PCHUNK = 64;
__global__ void pool_kernel(const u16* __restrict__ h, const int* __restrict__ batch,
                            float* __restrict__ pooled) {
    const int j = threadIdx.x;                 // 0..95
    const int c0 = blockIdx.x * PCHUNK;
    const int c1 = min(c0 + PCHUNK, Nn);
    if (c0 >= Nn) return;

    int bcur = batch[c0];
    float acc = 0.0f;
    for (int n = c0; n < c1; ++n) {
        const int bb = batch[n];
        if (bb != bcur) {
            atomicAdd(&pooled[(long)bcur * Hh + j], acc);
            acc = 0.0f;
            bcur = bb;
        }
        acc += bf2f(h[(long)n * Hh + j]);
    }
    atomicAdd(&pooled[(long)bcur * Hh + j], acc);
}

// ---------------------------------------------------------------------------
// Head: out[b] = dot(pooled[b], head_w[rt[b]]) + head_b[rt[b]]
// ---------------------------------------------------------------------------
__global__ void head_kernel(const float* __restrict__ pooled, const int* __restrict__ rt,
                            const float* __restrict__ hw, const float* __restrict__ hb,
                            float* __restrict__ outv) {
    const int b = blockIdx.x;
    const int lane = threadIdx.x;
    const int t = rt[b];
    const float* pp = pooled + (long)b * Hh;
    const float* wp = hw + (long)t * Hh;
    float s = 0.0f;
    for (int j = lane; j < Hh; j += 64) s += pp[j] * wp[j];
    #pragma unroll
    for (int off = 32; off > 0; off >>= 1) s += __shfl_down(s, off, 64);
    if (lane == 0) outv[b] = s + hb[t];
}

// ---------------------------------------------------------------------------
extern "C" void kernel_launch(void* const* d_in, const int* in_sizes, int n_in,
                              void* d_out, int out_size, void* d_ws, size_t ws_size,
                              hipStream_t stream) {
    const float* x     = (const float*)d_in[0];
    const int*   ei    = (const int*)d_in[1];      // [2, E] flattened int32
    const int*   src   = ei;
    const int*   dst   = ei + Ee;
    const int*   batch = (const int*)d_in[2];
    const int*   rt    = (const int*)d_in[3];

    const float* P[3][8];
    for (int l = 0; l < 3; ++l)
        for (int p = 0; p < 8; ++p)
            P[l][p] = (const float*)d_in[4 + l * 8 + p];
    const float* head_w = (const float*)d_in[28];
    const float* head_b = (const float*)d_in[29];

    // Workspace layout
    const size_t NH = (size_t)Nn * Hh;
    u16*   tA      = (u16*)d_ws;                       // N*H bf16
    u16*   tB      = tA + NH;                          // N*H bf16
    u16*   tG      = tB + NH;                          // N*H bf16
    u16*   xb      = tG + NH;                          // N*INF bf16
    float* pooled  = (float*)(xb + (size_t)Nn * INF);  // B*H fp32
    int*   rowptr  = (int*)(pooled + (size_t)Bb * Hh); // N+1 ints
    int*   counts  = rowptr + Nn + 1;                  // NBIN*P1B ints
    int*   binbase = counts + NBIN * P1B;              // NBIN ints
    u16*   csr     = (u16*)(binbase + NBIN);           // E u16
    // binbuf (12.8 MB) overlays tA+tB (19.2 MB) — both dead during CSR build
    u32*   binbuf  = (u32*)tA;
    float* out     = (float*)d_out;

    const dim3 blk256(256), blk96(96);
    const int GRID_T    = (Nn + 63) / 64;              // 782 tiles
    const int GRID_POOL = (Nn + PCHUNK - 1) / PCHUNK;

    // ----- x -> bf16 ; build CSR (binned two-level sort) -----
    x2bf_kernel<<<GRID_T, blk256, 0, stream>>>(x, xb);
    p1_bin_kernel<<<P1B, blk256, 0, stream>>>(src, dst, binbuf, counts);
    p2_binscan_kernel<<<1, blk256, 0, stream>>>(counts, binbase, rowptr);
    p3_binsort_kernel<<<NBIN, blk256, 0, stream>>>(binbuf, counts, binbase, rowptr, csr);

    // ----- Layer 1: fused agg+fc1(xb) -> tG ; fc2 -> tA -----
    fused_agg_fc1_kernel<INF><<<GRID_T, blk256, 0, stream>>>(xb, rowptr, csr,
        P[0][0], P[0][1], P[0][2], P[0][3], P[0][4], P[0][5], tG);
    fc2_kernel<<<GRID_T, blk256, 0, stream>>>(tG, P[0][6], P[0][7], tA);

    // ----- Layer 2: fused agg+fc1(tA) -> tG ; fc2 -> tB -----
    fused_agg_fc1_kernel<Hh><<<GRID_T, blk256, 0, stream>>>(tA, rowptr, csr,
        P[1][0], P[1][1], P[1][2], P[1][3], P[1][4], P[1][5], tG);
    fc2_kernel<<<GRID_T, blk256, 0, stream>>>(tG, P[1][6], P[1][7], tB);

    // ----- Layer 3: fused agg+fc1(tB) -> tG ; fc2 -> tA -----
    fused_agg_fc1_kernel<Hh><<<GRID_T, blk256, 0, stream>>>(tB, rowptr, csr,
        P[2][0], P[2][1], P[2][2], P[2][3], P[2][4], P[2][5], tG);
    fc2_kernel<<<GRID_T, blk256, 0, stream>>>(tG, P[2][6], P[2][7], tA);

    // ----- Pool (chunked) + head -----
    hipMemsetAsync(pooled, 0, (size_t)Bb * Hh * sizeof(float), stream);
    pool_kernel<<<GRID_POOL, blk96, 0, stream>>>(tA, batch, pooled);
    head_kernel<<<Bb, 64, 0, stream>>>(pooled, rt, head_w, head_b, out);
}

// Round 11
// 275.388 us; speedup vs baseline: 1.0393x; 1.0393x over previous
//
#include <hip/hip_runtime.h>

using u16 = unsigned short;
using u32 = unsigned int;

// Problem constants (from reference)
constexpr int Nn  = 50000;   // nodes
constexpr int Ee  = 800000;  // edges
constexpr int Bb  = 256;     // graphs
constexpr int INF = 32;      // input feature dim
constexpr int Hh  = 96;      // hidden dim
constexpr float BN_EPS = 1e-5f;

// Binned CSR build parameters
constexpr int BINW = 256;                      // nodes per bin
constexpr int NBIN = (Nn + BINW - 1) / BINW;   // 196
constexpr int P1B  = 256;                      // pass-1 blocks
constexpr int EPB  = Ee / P1B;                 // 3125 edges per block (exact)
constexpr int CAP  = 64;                       // per (block,bin) capacity (mean 16, 12 sigma)

// bf16 weight table offsets (u16 units), k-pair-interleaved layout:
//   u32 word i = { lo: w[2*k2][j], hi: w[2*k2+1][j] },  i = base/2 + k2*96 + j
constexpr int W1I_OFF = 0;        // 32*96  = 3072
constexpr int W1O_OFF = 3072;     // 96*96  = 9216
constexpr int W2I_OFF = 12288;
constexpr int W2O_OFF = 21504;
constexpr int W3I_OFF = 30720;
constexpr int W3O_OFF = 39936;
constexpr int WB_TOT  = 49152;    // u16 total

// ---------------- bf16 helpers (rne) ----------------
__device__ __forceinline__ float bfL(u32 u) { return __uint_as_float(u << 16); }
__device__ __forceinline__ float bfH(u32 u) { return __uint_as_float(u & 0xFFFF0000u); }
__device__ __forceinline__ u32 f2bfb(float f) {            // rounded bf16 bits (low 16)
    u32 b = __float_as_uint(f);
    return (b + 0x7FFFu + ((b >> 16) & 1u)) >> 16;
}
__device__ __forceinline__ float bf2f(u16 u) { return __uint_as_float(((u32)u) << 16); }

// ---------------------------------------------------------------------------
// x -> bf16 table (N x 32)
// ---------------------------------------------------------------------------
__global__ void x2bf_kernel(const float* __restrict__ x, u16* __restrict__ xb) {
    const int total = Nn * INF / 8;
    for (int i = blockIdx.x * 256 + threadIdx.x; i < total; i += gridDim.x * 256) {
        const float4 a = ((const float4*)x)[2 * i];
        const float4 b = ((const float4*)x)[2 * i + 1];
        uint4 R;
        R.x = f2bfb(a.x) | (f2bfb(a.y) << 16);
        R.y = f2bfb(a.z) | (f2bfb(a.w) << 16);
        R.z = f2bfb(b.x) | (f2bfb(b.y) << 16);
        R.w = f2bfb(b.z) | (f2bfb(b.w) << 16);
        ((uint4*)xb)[i] = R;
    }
}

// ---------------------------------------------------------------------------
// Weights -> bf16, k-pair interleaved. One u32 output per thread.
// ---------------------------------------------------------------------------
__global__ void w2bf_kernel(const float* __restrict__ w1i, const float* __restrict__ w1o,
                            const float* __restrict__ w2i, const float* __restrict__ w2o,
                            const float* __restrict__ w3i, const float* __restrict__ w3o,
                            u16* __restrict__ wb) {
    const int i = blockIdx.x * 256 + threadIdx.x;     // u32 index
    if (i >= WB_TOT / 2) return;
    const float* src; int base;
    if      (i < 1536)  { src = w1i; base = 0;     }
    else if (i < 6144)  { src = w1o; base = 1536;  }
    else if (i < 10752) { src = w2i; base = 6144;  }
    else if (i < 15360) { src = w2o; base = 10752; }
    else if (i < 19968) { src = w3i; base = 15360; }
    else                { src = w3o; base = 19968; }
    const int local = i - base;
    const int k2 = local / 96, j = local % 96;
    ((u32*)wb)[i] = f2bfb(src[(2 * k2) * 96 + j]) | (f2bfb(src[(2 * k2 + 1) * 96 + j]) << 16);
}

// ---------------------------------------------------------------------------
// CSR build pass 1: bin edges into per-(block,bin) private regions.
// ---------------------------------------------------------------------------
__global__ __launch_bounds__(256)
void p1_bin_kernel(const int* __restrict__ src, const int* __restrict__ dst,
                   u32* __restrict__ binbuf, int* __restrict__ counts) {
    __shared__ int cur[NBIN];
    const int b = blockIdx.x, tid = threadIdx.x;
    for (int k = tid; k < NBIN; k += 256) cur[k] = 0;
    __syncthreads();
    const long e0 = (long)b * EPB;
    for (int i = tid; i < EPB; i += 256) {
        const long e = e0 + i;
        const int d = dst[e];
        const int k = d >> 8;
        const int pos = atomicAdd(&cur[k], 1);
        binbuf[((long)b * NBIN + k) * CAP + pos] = ((u32)(d & 255) << 16) | (u32)src[e];
    }
    __syncthreads();
    for (int k = tid; k < NBIN; k += 256) counts[k * P1B + b] = cur[k];
}

// ---------------------------------------------------------------------------
// CSR build pass 2: bin totals -> exclusive prefix (binbase); rowptr[N] = E.
// ---------------------------------------------------------------------------
__global__ void p2_binscan_kernel(const int* __restrict__ counts, int* __restrict__ binbase,
                                  int* __restrict__ rowptr) {
    __shared__ int ps[256];
    const int t = threadIdx.x;
    int tot = 0;
    if (t < NBIN) {
        const int* cp = counts + t * P1B;
        for (int b = 0; b < P1B; ++b) tot += cp[b];
    }
    ps[t] = tot;
    __syncthreads();
    for (int d = 1; d < 256; d <<= 1) {
        int u = (t >= d) ? ps[t - d] : 0;
        __syncthreads();
        if (t >= d) ps[t] += u;
        __syncthreads();
    }
    if (t < NBIN) binbase[t] = ps[t] - tot;   // exclusive prefix
    if (t == 0) rowptr[Nn] = Ee;
}

// ---------------------------------------------------------------------------
// CSR build pass 3: one block per bin -> rowptr slice + sorted u16 csr window.
// ---------------------------------------------------------------------------
__global__ __launch_bounds__(256)
void p3_binsort_kernel(const u32* __restrict__ binbuf, const int* __restrict__ counts,
                       const int* __restrict__ binbase, int* __restrict__ rowptr,
                       u16* __restrict__ csr) {
    __shared__ int cnt[P1B];
    __shared__ int lhist[BINW];
    __shared__ int lpref[BINW];
    const int k = blockIdx.x, tid = threadIdx.x;

    for (int b = tid; b < P1B; b += 256) cnt[b] = counts[k * P1B + b];
    lhist[tid] = 0;
    __syncthreads();

    for (int flat = tid; flat < P1B * CAP; flat += 256) {
        const int b = flat / CAP, i = flat % CAP;
        if (i < cnt[b])
            atomicAdd(&lhist[binbuf[((long)b * NBIN + k) * CAP + i] >> 16], 1);
    }
    __syncthreads();

    const int v = lhist[tid];
    lpref[tid] = v;
    __syncthreads();
    for (int d = 1; d < 256; d <<= 1) {
        int u = (tid >= d) ? lpref[tid - d] : 0;
        __syncthreads();
        if (tid >= d) lpref[tid] += u;
        __syncthreads();
    }
    lpref[tid] -= v;

    const int base = binbase[k];
    const int node = k * BINW + tid;
    if (node < Nn) rowptr[node] = base + lpref[tid];
    lhist[tid] = 0;                         // reuse as cursor
    __syncthreads();

    for (int flat = tid; flat < P1B * CAP; flat += 256) {
        const int b = flat / CAP, i = flat % CAP;
        if (i < cnt[b]) {
            const u32 pv = binbuf[((long)b * NBIN + k) * CAP + i];
            const int dl = pv >> 16;
            const int pos = base + lpref[dl] + atomicAdd(&lhist[dl], 1);
            csr[pos] = (u16)(pv & 0xFFFFu);
        }
    }
}

// ---------------------------------------------------------------------------
// FUSED agg + FC1 + BN + ReLU. 16-node tile, 192 threads.
// Gather: 12 threads/node (DIN=96, uint4 slot each) or 8 (DIN=32, uint2),
// 4x-unrolled edge loop. Weights: LDS bf16, k-pair interleaved (1 b64/k-pair).
// GEMM: thread = (nt = tid/48 -> 4 nodes) x (jt = tid%48 -> 2 feats).
// ---------------------------------------------------------------------------
template<int DIN>
__global__ __launch_bounds__(192, 5)
void fused_agg_fc1_kernel(const u16* __restrict__ hsrc, const int* __restrict__ rowptr,
                          const u16* __restrict__ csr, const u16* __restrict__ wbg,
                          const float* __restrict__ b_in,
                          const float* __restrict__ gamma, const float* __restrict__ beta,
                          const float* __restrict__ rmean, const float* __restrict__ rvar,
                          u16* __restrict__ out) {
    constexpr int TILE = 16;
    constexpr int XSTU = DIN + 2;             // u16 stride (98 or 34)
    __shared__ u16 wb[DIN * Hh];              // bf16 weights, k-pair layout
    __shared__ u16 xs[TILE * XSTU];           // bf16 x tile (k-contiguous rows)

    const int tid = threadIdx.x;
    const int nbase = blockIdx.x * TILE;

    // stage weights (global bf16 -> LDS), 16B chunks
    for (int i = tid; i < DIN * Hh / 8; i += 192)
        ((uint4*)wb)[i] = ((const uint4*)wbg)[i];

    // ---- gather phase ----
    {
        const int grp = tid / 12, ln = tid % 12;
        const int node = nbase + grp;
        if (node < Nn) {
            const int e0 = rowptr[node], e1 = rowptr[node + 1];
            if constexpr (DIN == 96) {
                const uint4* h4 = (const uint4*)hsrc;     // row = 12 uint4
                float a0, a1, a2, a3, a4, a5, a6, a7;
                {
                    const uint4 U = h4[(long)node * 12 + ln];
                    a0 = bfL(U.x); a1 = bfH(U.x); a2 = bfL(U.y); a3 = bfH(U.y);
                    a4 = bfL(U.z); a5 = bfH(U.z); a6 = bfL(U.w); a7 = bfH(U.w);
                }
                int e = e0;
                for (; e + 4 <= e1; e += 4) {
                    const long s0 = csr[e], s1 = csr[e + 1], s2 = csr[e + 2], s3 = csr[e + 3];
                    const uint4 U0 = h4[s0 * 12 + ln];
                    const uint4 U1 = h4[s1 * 12 + ln];
                    const uint4 U2 = h4[s2 * 12 + ln];
                    const uint4 U3 = h4[s3 * 12 + ln];
                    a0 += bfL(U0.x); a1 += bfH(U0.x); a2 += bfL(U0.y); a3 += bfH(U0.y);
                    a4 += bfL(U0.z); a5 += bfH(U0.z); a6 += bfL(U0.w); a7 += bfH(U0.w);
                    a0 += bfL(U1.x); a1 += bfH(U1.x); a2 += bfL(U1.y); a3 += bfH(U1.y);
                    a4 += bfL(U1.z); a5 += bfH(U1.z); a6 += bfL(U1.w); a7 += bfH(U1.w);
                    a0 += bfL(U2.x); a1 += bfH(U2.x); a2 += bfL(U2.y); a3 += bfH(U2.y);
                    a4 += bfL(U2.z); a5 += bfH(U2.z); a6 += bfL(U2.w); a7 += bfH(U2.w);
                    a0 += bfL(U3.x); a1 += bfH(U3.x); a2 += bfL(U3.y); a3 += bfH(U3.y);
                    a4 += bfL(U3.z); a5 += bfH(U3.z); a6 += bfL(U3.w); a7 += bfH(U3.w);
                }
                for (; e < e1; ++e) {
                    const uint4 U = h4[(long)csr[e] * 12 + ln];
                    a0 += bfL(U.x); a1 += bfH(U.x); a2 += bfL(U.y); a3 += bfH(U.y);
                    a4 += bfL(U.z); a5 += bfH(U.z); a6 += bfL(U.w); a7 += bfH(U.w);
                }
                u32* xp = (u32*)&xs[grp * XSTU + ln * 8];
                xp[0] = f2bfb(a0) | (f2bfb(a1) << 16);
                xp[1] = f2bfb(a2) | (f2bfb(a3) << 16);
                xp[2] = f2bfb(a4) | (f2bfb(a5) << 16);
                xp[3] = f2bfb(a6) | (f2bfb(a7) << 16);
            } else {                                      // DIN == 32
                if (ln < 8) {
                    const uint2* h2 = (const uint2*)hsrc; // row = 8 uint2
                    float a0, a1, a2, a3;
                    {
                        const uint2 U = h2[(long)node * 8 + ln];
                        a0 = bfL(U.x); a1 = bfH(U.x); a2 = bfL(U.y); a3 = bfH(U.y);
                    }
                    int e = e0;
                    for (; e + 4 <= e1; e += 4) {
                        const long s0 = csr[e], s1 = csr[e + 1], s2 = csr[e + 2], s3 = csr[e + 3];
                        const uint2 U0 = h2[s0 * 8 + ln];
                        const uint2 U1 = h2[s1 * 8 + ln];
                        const uint2 U2 = h2[s2 * 8 + ln];
                        const uint2 U3 = h2[s3 * 8 + ln];
                        a0 += bfL(U0.x); a1 += bfH(U0.x); a2 += bfL(U0.y); a3 += bfH(U0.y);
                        a0 += bfL(U1.x); a1 += bfH(U1.x); a2 += bfL(U1.y); a3 += bfH(U1.y);
                        a0 += bfL(U2.x); a1 += bfH(U2.x); a2 += bfL(U2.y); a3 += bfH(U2.y);
                        a0 += bfL(U3.x); a1 += bfH(U3.x); a2 += bfL(U3.y); a3 += bfH(U3.y);
                    }
                    for (; e < e1; ++e) {
                        const uint2 U = h2[(long)csr[e] * 8 + ln];
                        a0 += bfL(U.x); a1 += bfH(U.x); a2 += bfL(U.y); a3 += bfH(U.y);
                    }
                    u32* xp = (u32*)&xs[grp * XSTU + ln * 4];
                    xp[0] = f2bfb(a0) | (f2bfb(a1) << 16);
                    xp[1] = f2bfb(a2) | (f2bfb(a3) << 16);
                }
            }
        }
    }

    // ---- GEMM phase ----
    const int jt = tid % 48, nt = tid / 48;   // jt -> 2 feats, nt -> 4 nodes
    const int j0 = jt * 2;
    float A0, A1, C0, C1;
    {
        const float s0 = gamma[j0] * rsqrtf(rvar[j0] + BN_EPS);
        const float s1 = gamma[j0 + 1] * rsqrtf(rvar[j0 + 1] + BN_EPS);
        A0 = s0; C0 = (b_in[j0] - rmean[j0]) * s0 + beta[j0];
        A1 = s1; C1 = (b_in[j0 + 1] - rmean[j0 + 1]) * s1 + beta[j0 + 1];
    }
    __syncthreads();

    float acc[4][2] = {};
    #pragma unroll 4
    for (int k2 = 0; k2 < DIN / 2; ++k2) {
        float xlo[4], xhi[4];
        #pragma unroll
        for (int ni = 0; ni < 4; ++ni) {
            const u32 xv = *(const u32*)&xs[(nt * 4 + ni) * XSTU + 2 * k2];
            xlo[ni] = bfL(xv); xhi[ni] = bfH(xv);
        }
        const uint2 wv = *(const uint2*)&((const u32*)wb)[k2 * 96 + j0];
        const float wlo0 = bfL(wv.x), whi0 = bfH(wv.x);
        const float wlo1 = bfL(wv.y), whi1 = bfH(wv.y);
        #pragma unroll
        for (int ni = 0; ni < 4; ++ni) {
            acc[ni][0] = fmaf(xlo[ni], wlo0, acc[ni][0]);
            acc[ni][0] = fmaf(xhi[ni], whi0, acc[ni][0]);
            acc[ni][1] = fmaf(xlo[ni], wlo1, acc[ni][1]);
            acc[ni][1] = fmaf(xhi[ni], whi1, acc[ni][1]);
        }
    }

    #pragma unroll
    for (int ni = 0; ni < 4; ++ni) {
        const int node = nbase + nt * 4 + ni;
        if (node < Nn) {
            const float r0 = fmaxf(fmaf(acc[ni][0], A0, C0), 0.0f);
            const float r1 = fmaxf(fmaf(acc[ni][1], A1, C1), 0.0f);
            *(u32*)(out + (long)node * Hh + j0) = f2bfb(r0) | (f2bfb(r1) << 16);
        }
    }
}

// ---------------------------------------------------------------------------
// FC2 + ReLU (bf16 in/out). 32-node tile, 256 threads, k-pair bf16 weights.
// Thread = (nt = tid/16 -> 2 nodes) x (jt = tid%16 -> 6 feats).
// ---------------------------------------------------------------------------
__global__ __launch_bounds__(256, 5)
void fc2_kernel(const u16* __restrict__ xin, const u16* __restrict__ wbg,
                const float* __restrict__ b_out, u16* __restrict__ out) {
    constexpr int DIN  = Hh;
    constexpr int XSTU = DIN + 2;             // 98
    constexpr int TILE = 32;
    __shared__ u16 wb[DIN * Hh];
    __shared__ u16 xs[TILE * XSTU];

    const int tid = threadIdx.x;
    const int jt  = tid & 15;
    const int nt  = tid >> 4;
    const int j0  = jt * 6;
    const int nbase = blockIdx.x * TILE;

    for (int i = tid; i < DIN * Hh / 8; i += 256)
        ((uint4*)wb)[i] = ((const uint4*)wbg)[i];

    for (int idx = tid; idx < TILE * 12; idx += 256) {
        const int r = idx / 12, c = idx % 12;
        const int gr = nbase + r;
        uint4 U = make_uint4(0u, 0u, 0u, 0u);
        if (gr < Nn) U = ((const uint4*)(xin + (long)gr * DIN))[c];
        u32* xp = (u32*)&xs[r * XSTU + c * 8];
        xp[0] = U.x; xp[1] = U.y; xp[2] = U.z; xp[3] = U.w;
    }

    float C[6];
    #pragma unroll
    for (int ji = 0; ji < 6; ++ji) C[ji] = b_out[j0 + ji];
    __syncthreads();

    float acc[2][6] = {};
    #pragma unroll 4
    for (int k2 = 0; k2 < DIN / 2; ++k2) {
        float xlo[2], xhi[2];
        #pragma unroll
        for (int ni = 0; ni < 2; ++ni) {
            const u32 xv = *(const u32*)&xs[(nt * 2 + ni) * XSTU + 2 * k2];
            xlo[ni] = bfL(xv); xhi[ni] = bfH(xv);
        }
        float wlo[6], whi[6];
        #pragma unroll
        for (int q = 0; q < 3; ++q) {
            const uint2 wv = *(const uint2*)&((const u32*)wb)[k2 * 96 + j0 + 2 * q];
            wlo[2 * q]     = bfL(wv.x); whi[2 * q]     = bfH(wv.x);
            wlo[2 * q + 1] = bfL(wv.y); whi[2 * q + 1] = bfH(wv.y);
        }
        #pragma unroll
        for (int ni = 0; ni < 2; ++ni)
            #pragma unroll
            for (int ji = 0; ji < 6; ++ji) {
                acc[ni][ji] = fmaf(xlo[ni], wlo[ji], acc[ni][ji]);
                acc[ni][ji] = fmaf(xhi[ni], whi[ji], acc[ni][ji]);
            }
    }

    #pragma unroll
    for (int ni = 0; ni < 2; ++ni) {
        const int node = nbase + nt * 2 + ni;
        if (node < Nn) {
            u16* op = out + (long)node * Hh + j0;
            #pragma unroll
            for (int q = 0; q < 3; ++q) {
                const float r0 = fmaxf(acc[ni][2 * q]     + C[2 * q],     0.0f);
                const float r1 = fmaxf(acc[ni][2 * q + 1] + C[2 * q + 1], 0.0f);
                *(u32*)(op + 2 * q) = f2bfb(r0) | (f2bfb(r1) << 16);
            }
        }
    }
}

// ---------------------------------------------------------------------------
// Chunked pooling over bf16 table (batch sorted; boundary-flush atomics)
// ---------------------------------------------------------------------------
constexpr int PCHUNK = 64;
__global__ void pool_kernel(const u16* __restrict__ h, const int* __restrict__ batch,
                            float* __restrict__ pooled) {
    const int j = threadIdx.x;                 // 0..95
    const int c0 = blockIdx.x * PCHUNK;
    const int c1 = min(c0 + PCHUNK, Nn);
    if (c0 >= Nn) return;

    int bcur = batch[c0];
    float acc = 0.0f;
    for (int n = c0; n < c1; ++n) {
        const int bb = batch[n];
        if (bb != bcur) {
            atomicAdd(&pooled[(long)bcur * Hh + j], acc);
            acc = 0.0f;
            bcur = bb;
        }
        acc += bf2f(h[(long)n * Hh + j]);
    }
    atomicAdd(&pooled[(long)bcur * Hh + j], acc);
}

// ---------------------------------------------------------------------------
// Head: out[b] = dot(pooled[b], head_w[rt[b]]) + head_b[rt[b]]
// ---------------------------------------------------------------------------
__global__ void head_kernel(const float* __restrict__ pooled, const int* __restrict__ rt,
                            const float* __restrict__ hw, const float* __restrict__ hb,
                            float* __restrict__ outv) {
    const int b = blockIdx.x;
    const int lane = threadIdx.x;
    const int t = rt[b];
    const float* pp = pooled + (long)b * Hh;
    const float* wp = hw + (long)t * Hh;
    float s = 0.0f;
    for (int j = lane; j < Hh; j += 64) s += pp[j] * wp[j];
    #pragma unroll
    for (int off = 32; off > 0; off >>= 1) s += __shfl_down(s, off, 64);
    if (lane == 0) outv[b] = s + hb[t];
}

// ---------------------------------------------------------------------------
extern "C" void kernel_launch(void* const* d_in, const int* in_sizes, int n_in,
                              void* d_out, int out_size, void* d_ws, size_t ws_size,
                              hipStream_t stream) {
    const float* x     = (const float*)d_in[0];
    const int*   ei    = (const int*)d_in[1];      // [2, E] flattened int32
    const int*   src   = ei;
    const int*   dst   = ei + Ee;
    const int*   batch = (const int*)d_in[2];
    const int*   rt    = (const int*)d_in[3];

    const float* P[3][8];
    for (int l = 0; l < 3; ++l)
        for (int p = 0; p < 8; ++p)
            P[l][p] = (const float*)d_in[4 + l * 8 + p];
    const float* head_w = (const float*)d_in[28];
    const float* head_b = (const float*)d_in[29];

    // Workspace layout
    const size_t NH = (size_t)Nn * Hh;
    u16*   tA      = (u16*)d_ws;                       // N*H bf16
    u16*   tB      = tA + NH;                          // N*H bf16
    u16*   tG      = tB + NH;                          // N*H bf16
    u16*   xb      = tG + NH;                          // N*INF bf16
    u16*   wball   = xb + (size_t)Nn * INF;            // WB_TOT u16
    float* pooled  = (float*)(wball + WB_TOT);         // B*H fp32
    int*   rowptr  = (int*)(pooled + (size_t)Bb * Hh); // N+1 ints
    int*   counts  = rowptr + Nn + 1;                  // NBIN*P1B ints
    int*   binbase = counts + NBIN * P1B;              // NBIN ints
    u16*   csr     = (u16*)(binbase + NBIN);           // E u16
    // binbuf (12.8 MB) overlays tA+tB (19.2 MB) — both dead during CSR build
    u32*   binbuf  = (u32*)tA;
    float* out     = (float*)d_out;

    const dim3 blk256(256), blk192(192), blk96(96);
    const int GRID_F1   = Nn / 16;                     // 3125 (exact)
    const int GRID_FC2  = (Nn + 31) / 32;              // 1563
    const int GRID_POOL = (Nn + PCHUNK - 1) / PCHUNK;

    // ----- precompute tables ; build CSR -----
    x2bf_kernel<<<782, blk256, 0, stream>>>(x, xb);
    w2bf_kernel<<<(WB_TOT / 2 + 255) / 256, blk256, 0, stream>>>(
        P[0][0], P[0][6], P[1][0], P[1][6], P[2][0], P[2][6], wball);
    p1_bin_kernel<<<P1B, blk256, 0, stream>>>(src, dst, binbuf, counts);
    p2_binscan_kernel<<<1, blk256, 0, stream>>>(counts, binbase, rowptr);
    p3_binsort_kernel<<<NBIN, blk256, 0, stream>>>(binbuf, counts, binbase, rowptr, csr);

    // ----- Layer 1: fused agg+fc1(xb) -> tG ; fc2 -> tA -----
    fused_agg_fc1_kernel<INF><<<GRID_F1, blk192, 0, stream>>>(xb, rowptr, csr,
        wball + W1I_OFF, P[0][1], P[0][2], P[0][3], P[0][4], P[0][5], tG);
    fc2_kernel<<<GRID_FC2, blk256, 0, stream>>>(tG, wball + W1O_OFF, P[0][7], tA);

    // ----- Layer 2: fused agg+fc1(tA) -> tG ; fc2 -> tB -----
    fused_agg_fc1_kernel<Hh><<<GRID_F1, blk192, 0, stream>>>(tA, rowptr, csr,
        wball + W2I_OFF, P[1][1], P[1][2], P[1][3], P[1][4], P[1][5], tG);
    fc2_kernel<<<GRID_FC2, blk256, 0, stream>>>(tG, wball + W2O_OFF, P[1][7], tB);

    // ----- Layer 3: fused agg+fc1(tB) -> tG ; fc2 -> tA -----
    fused_agg_fc1_kernel<Hh><<<GRID_F1, blk192, 0, stream>>>(tB, rowptr, csr,
        wball + W3I_OFF, P[2][1], P[2][2], P[2][3], P[2][4], P[2][5], tG);
    fc2_kernel<<<GRID_FC2, blk256, 0, stream>>>(tG, wball + W3O_OFF, P[2][7], tA);

    // ----- Pool (chunked) + head -----
    hipMemsetAsync(pooled, 0, (size_t)Bb * Hh * sizeof(float), stream);
    pool_kernel<<<GRID_POOL, blk96, 0, stream>>>(tA, batch, pooled);
    head_kernel<<<Bb, 64, 0, stream>>>(pooled, rt, head_w, head_b, out);
}

// Round 12
// 262.664 us; speedup vs baseline: 1.0896x; 1.0484x over previous
//
#include <hip/hip_runtime.h>

using u16 = unsigned short;
using u32 = unsigned int;

// Problem constants (from reference)
constexpr int Nn  = 50000;   // nodes
constexpr int Ee  = 800000;  // edges
constexpr int Bb  = 256;     // graphs
constexpr int INF = 32;      // input feature dim
constexpr int Hh  = 96;      // hidden dim
constexpr float BN_EPS = 1e-5f;

// Binned CSR build parameters
constexpr int BINW = 256;                      // nodes per bin
constexpr int NBIN = (Nn + BINW - 1) / BINW;   // 196
constexpr int P1B  = 256;                      // pass-1 blocks
constexpr int EPB  = Ee / P1B;                 // 3125 edges per block (exact)
constexpr int CAP  = 64;                       // per (block,bin) capacity (mean 16, 12 sigma)

// bf16 weight table offsets (u16 units), k-pair-interleaved layout:
//   u32 word i = { lo: w[2*k2][j], hi: w[2*k2+1][j] },  i = base/2 + k2*96 + j
constexpr int W1I_OFF = 0;        // 32*96  = 3072
constexpr int W1O_OFF = 3072;     // 96*96  = 9216
constexpr int W2I_OFF = 12288;
constexpr int W2O_OFF = 21504;
constexpr int W3I_OFF = 30720;
constexpr int W3O_OFF = 39936;
constexpr int WB_TOT  = 49152;    // u16 total

// ---------------- bf16 helpers (rne) ----------------
__device__ __forceinline__ float bfL(u32 u) { return __uint_as_float(u << 16); }
__device__ __forceinline__ float bfH(u32 u) { return __uint_as_float(u & 0xFFFF0000u); }
__device__ __forceinline__ u32 f2bfb(float f) {            // rounded bf16 bits (low 16)
    u32 b = __float_as_uint(f);
    return (b + 0x7FFFu + ((b >> 16) & 1u)) >> 16;
}
__device__ __forceinline__ float bf2f(u16 u) { return __uint_as_float(((u32)u) << 16); }

// ---------------------------------------------------------------------------
// x -> bf16 table (N x 32)
// ---------------------------------------------------------------------------
__global__ void x2bf_kernel(const float* __restrict__ x, u16* __restrict__ xb) {
    const int total = Nn * INF / 8;
    for (int i = blockIdx.x * 256 + threadIdx.x; i < total; i += gridDim.x * 256) {
        const float4 a = ((const float4*)x)[2 * i];
        const float4 b = ((const float4*)x)[2 * i + 1];
        uint4 R;
        R.x = f2bfb(a.x) | (f2bfb(a.y) << 16);
        R.y = f2bfb(a.z) | (f2bfb(a.w) << 16);
        R.z = f2bfb(b.x) | (f2bfb(b.y) << 16);
        R.w = f2bfb(b.z) | (f2bfb(b.w) << 16);
        ((uint4*)xb)[i] = R;
    }
}

// ---------------------------------------------------------------------------
// Weights -> bf16, k-pair interleaved. One u32 output per thread.
// ---------------------------------------------------------------------------
__global__ void w2bf_kernel(const float* __restrict__ w1i, const float* __restrict__ w1o,
                            const float* __restrict__ w2i, const float* __restrict__ w2o,
                            const float* __restrict__ w3i, const float* __restrict__ w3o,
                            u16* __restrict__ wb) {
    const int i = blockIdx.x * 256 + threadIdx.x;     // u32 index
    if (i >= WB_TOT / 2) return;
    const float* src; int base;
    if      (i < 1536)  { src = w1i; base = 0;     }
    else if (i < 6144)  { src = w1o; base = 1536;  }
    else if (i < 10752) { src = w2i; base = 6144;  }
    else if (i < 15360) { src = w2o; base = 10752; }
    else if (i < 19968) { src = w3i; base = 15360; }
    else                { src = w3o; base = 19968; }
    const int local = i - base;
    const int k2 = local / 96, j = local % 96;
    ((u32*)wb)[i] = f2bfb(src[(2 * k2) * 96 + j]) | (f2bfb(src[(2 * k2 + 1) * 96 + j]) << 16);
}

// ---------------------------------------------------------------------------
// CSR build pass 1: bin edges into per-(block,bin) private regions.
// ---------------------------------------------------------------------------
__global__ __launch_bounds__(256)
void p1_bin_kernel(const int* __restrict__ src, const int* __restrict__ dst,
                   u32* __restrict__ binbuf, int* __restrict__ counts) {
    __shared__ int cur[NBIN];
    const int b = blockIdx.x, tid = threadIdx.x;
    for (int k = tid; k < NBIN; k += 256) cur[k] = 0;
    __syncthreads();
    const long e0 = (long)b * EPB;
    for (int i = tid; i < EPB; i += 256) {
        const long e = e0 + i;
        const int d = dst[e];
        const int k = d >> 8;
        const int pos = atomicAdd(&cur[k], 1);
        binbuf[((long)b * NBIN + k) * CAP + pos] = ((u32)(d & 255) << 16) | (u32)src[e];
    }
    __syncthreads();
    for (int k = tid; k < NBIN; k += 256) counts[k * P1B + b] = cur[k];
}

// ---------------------------------------------------------------------------
// CSR build pass 2: bin totals -> exclusive prefix (binbase); rowptr[N] = E.
// ---------------------------------------------------------------------------
__global__ void p2_binscan_kernel(const int* __restrict__ counts, int* __restrict__ binbase,
                                  int* __restrict__ rowptr) {
    __shared__ int ps[256];
    const int t = threadIdx.x;
    int tot = 0;
    if (t < NBIN) {
        const int* cp = counts + t * P1B;
        for (int b = 0; b < P1B; ++b) tot += cp[b];
    }
    ps[t] = tot;
    __syncthreads();
    for (int d = 1; d < 256; d <<= 1) {
        int u = (t >= d) ? ps[t - d] : 0;
        __syncthreads();
        if (t >= d) ps[t] += u;
        __syncthreads();
    }
    if (t < NBIN) binbase[t] = ps[t] - tot;   // exclusive prefix
    if (t == 0) rowptr[Nn] = Ee;
}

// ---------------------------------------------------------------------------
// CSR build pass 3: one block per bin -> rowptr slice + sorted u16 csr window.
// ---------------------------------------------------------------------------
__global__ __launch_bounds__(256)
void p3_binsort_kernel(const u32* __restrict__ binbuf, const int* __restrict__ counts,
                       const int* __restrict__ binbase, int* __restrict__ rowptr,
                       u16* __restrict__ csr) {
    __shared__ int cnt[P1B];
    __shared__ int lhist[BINW];
    __shared__ int lpref[BINW];
    const int k = blockIdx.x, tid = threadIdx.x;

    for (int b = tid; b < P1B; b += 256) cnt[b] = counts[k * P1B + b];
    lhist[tid] = 0;
    __syncthreads();

    for (int flat = tid; flat < P1B * CAP; flat += 256) {
        const int b = flat / CAP, i = flat % CAP;
        if (i < cnt[b])
            atomicAdd(&lhist[binbuf[((long)b * NBIN + k) * CAP + i] >> 16], 1);
    }
    __syncthreads();

    const int v = lhist[tid];
    lpref[tid] = v;
    __syncthreads();
    for (int d = 1; d < 256; d <<= 1) {
        int u = (tid >= d) ? lpref[tid - d] : 0;
        __syncthreads();
        if (tid >= d) lpref[tid] += u;
        __syncthreads();
    }
    lpref[tid] -= v;

    const int base = binbase[k];
    const int node = k * BINW + tid;
    if (node < Nn) rowptr[node] = base + lpref[tid];
    lhist[tid] = 0;                         // reuse as cursor
    __syncthreads();

    for (int flat = tid; flat < P1B * CAP; flat += 256) {
        const int b = flat / CAP, i = flat % CAP;
        if (i < cnt[b]) {
            const u32 pv = binbuf[((long)b * NBIN + k) * CAP + i];
            const int dl = pv >> 16;
            const int pos = base + lpref[dl] + atomicAdd(&lhist[dl], 1);
            csr[pos] = (u16)(pv & 0xFFFFu);
        }
    }
}

// ---------------------------------------------------------------------------
// FULL GIN LAYER: agg + FC1 + BN + ReLU + FC2 + ReLU, one 16-node tile/block.
// Phases (192 threads):
//   stage w_in -> gather (12 thr/node, 4x unroll) -> sync
//   GEMM1 (K=DIN) + BN + ReLU, z held in regs      -> sync
//   z -> xs tile (stride 98), wb <- w_out          -> sync
//   GEMM2 (K=96) + bias + ReLU -> global out
// LDS = 18.4 KB weights + 3.1 KB tile (~21.6 KB) -> ~7 blocks/CU.
// ---------------------------------------------------------------------------
template<int DIN>
__global__ __launch_bounds__(192, 5)
void layer_kernel(const u16* __restrict__ hsrc, const int* __restrict__ rowptr,
                  const u16* __restrict__ csr,
                  const u16* __restrict__ wbg1, const u16* __restrict__ wbg2,
                  const float* __restrict__ b_in,
                  const float* __restrict__ gamma, const float* __restrict__ beta,
                  const float* __restrict__ rmean, const float* __restrict__ rvar,
                  const float* __restrict__ b_out,
                  u16* __restrict__ out) {
    constexpr int TILE = 16;
    constexpr int XSTU = Hh + 2;              // 98, shared by gather/z tiles
    __shared__ u16 wb[Hh * Hh];               // holds w_in then w_out (k-pair)
    __shared__ u16 xs[TILE * XSTU];

    const int tid = threadIdx.x;
    const int nbase = blockIdx.x * TILE;      // Nn = 3125*16 exactly

    // stage w_in
    for (int i = tid; i < DIN * Hh / 8; i += 192)
        ((uint4*)wb)[i] = ((const uint4*)wbg1)[i];

    // ---- gather phase ----
    {
        const int grp = tid / 12, ln = tid % 12;
        const int node = nbase + grp;
        const int e0 = rowptr[node], e1 = rowptr[node + 1];
        if constexpr (DIN == 96) {
            const uint4* h4 = (const uint4*)hsrc;     // row = 12 uint4
            float a0, a1, a2, a3, a4, a5, a6, a7;
            {
                const uint4 U = h4[(long)node * 12 + ln];
                a0 = bfL(U.x); a1 = bfH(U.x); a2 = bfL(U.y); a3 = bfH(U.y);
                a4 = bfL(U.z); a5 = bfH(U.z); a6 = bfL(U.w); a7 = bfH(U.w);
            }
            int e = e0;
            for (; e + 4 <= e1; e += 4) {
                const long s0 = csr[e], s1 = csr[e + 1], s2 = csr[e + 2], s3 = csr[e + 3];
                const uint4 U0 = h4[s0 * 12 + ln];
                const uint4 U1 = h4[s1 * 12 + ln];
                const uint4 U2 = h4[s2 * 12 + ln];
                const uint4 U3 = h4[s3 * 12 + ln];
                a0 += bfL(U0.x); a1 += bfH(U0.x); a2 += bfL(U0.y); a3 += bfH(U0.y);
                a4 += bfL(U0.z); a5 += bfH(U0.z); a6 += bfL(U0.w); a7 += bfH(U0.w);
                a0 += bfL(U1.x); a1 += bfH(U1.x); a2 += bfL(U1.y); a3 += bfH(U1.y);
                a4 += bfL(U1.z); a5 += bfH(U1.z); a6 += bfL(U1.w); a7 += bfH(U1.w);
                a0 += bfL(U2.x); a1 += bfH(U2.x); a2 += bfL(U2.y); a3 += bfH(U2.y);
                a4 += bfL(U2.z); a5 += bfH(U2.z); a6 += bfL(U2.w); a7 += bfH(U2.w);
                a0 += bfL(U3.x); a1 += bfH(U3.x); a2 += bfL(U3.y); a3 += bfH(U3.y);
                a4 += bfL(U3.z); a5 += bfH(U3.z); a6 += bfL(U3.w); a7 += bfH(U3.w);
            }
            for (; e < e1; ++e) {
                const uint4 U = h4[(long)csr[e] * 12 + ln];
                a0 += bfL(U.x); a1 += bfH(U.x); a2 += bfL(U.y); a3 += bfH(U.y);
                a4 += bfL(U.z); a5 += bfH(U.z); a6 += bfL(U.w); a7 += bfH(U.w);
            }
            u32* xp = (u32*)&xs[grp * XSTU + ln * 8];
            xp[0] = f2bfb(a0) | (f2bfb(a1) << 16);
            xp[1] = f2bfb(a2) | (f2bfb(a3) << 16);
            xp[2] = f2bfb(a4) | (f2bfb(a5) << 16);
            xp[3] = f2bfb(a6) | (f2bfb(a7) << 16);
        } else {                                      // DIN == 32
            if (ln < 8) {
                const uint2* h2 = (const uint2*)hsrc; // row = 8 uint2
                float a0, a1, a2, a3;
                {
                    const uint2 U = h2[(long)node * 8 + ln];
                    a0 = bfL(U.x); a1 = bfH(U.x); a2 = bfL(U.y); a3 = bfH(U.y);
                }
                int e = e0;
                for (; e + 4 <= e1; e += 4) {
                    const long s0 = csr[e], s1 = csr[e + 1], s2 = csr[e + 2], s3 = csr[e + 3];
                    const uint2 U0 = h2[s0 * 8 + ln];
                    const uint2 U1 = h2[s1 * 8 + ln];
                    const uint2 U2 = h2[s2 * 8 + ln];
                    const uint2 U3 = h2[s3 * 8 + ln];
                    a0 += bfL(U0.x); a1 += bfH(U0.x); a2 += bfL(U0.y); a3 += bfH(U0.y);
                    a0 += bfL(U1.x); a1 += bfH(U1.x); a2 += bfL(U1.y); a3 += bfH(U1.y);
                    a0 += bfL(U2.x); a1 += bfH(U2.x); a2 += bfL(U2.y); a3 += bfH(U2.y);
                    a0 += bfL(U3.x); a1 += bfH(U3.x); a2 += bfL(U3.y); a3 += bfH(U3.y);
                }
                for (; e < e1; ++e) {
                    const uint2 U = h2[(long)csr[e] * 8 + ln];
                    a0 += bfL(U.x); a1 += bfH(U.x); a2 += bfL(U.y); a3 += bfH(U.y);
                }
                u32* xp = (u32*)&xs[grp * XSTU + ln * 4];
                xp[0] = f2bfb(a0) | (f2bfb(a1) << 16);
                xp[1] = f2bfb(a2) | (f2bfb(a3) << 16);
            }
        }
    }

    // thread tiling for both GEMMs: jt -> 2 feats, nt -> 4 nodes
    const int jt = tid % 48, nt = tid / 48;
    const int j0 = jt * 2;

    // BN constants (GEMM1 epilogue)
    float A0, A1, C0, C1;
    {
        const float s0 = gamma[j0] * rsqrtf(rvar[j0] + BN_EPS);
        const float s1 = gamma[j0 + 1] * rsqrtf(rvar[j0 + 1] + BN_EPS);
        A0 = s0; C0 = (b_in[j0] - rmean[j0]) * s0 + beta[j0];
        A1 = s1; C1 = (b_in[j0 + 1] - rmean[j0 + 1]) * s1 + beta[j0 + 1];
    }
    __syncthreads();

    // ---- GEMM1 (K = DIN) ----
    float acc[4][2] = {};
    #pragma unroll 4
    for (int k2 = 0; k2 < DIN / 2; ++k2) {
        float xlo[4], xhi[4];
        #pragma unroll
        for (int ni = 0; ni < 4; ++ni) {
            const u32 xv = *(const u32*)&xs[(nt * 4 + ni) * XSTU + 2 * k2];
            xlo[ni] = bfL(xv); xhi[ni] = bfH(xv);
        }
        const uint2 wv = *(const uint2*)&((const u32*)wb)[k2 * 96 + j0];
        const float wlo0 = bfL(wv.x), whi0 = bfH(wv.x);
        const float wlo1 = bfL(wv.y), whi1 = bfH(wv.y);
        #pragma unroll
        for (int ni = 0; ni < 4; ++ni) {
            acc[ni][0] = fmaf(xlo[ni], wlo0, acc[ni][0]);
            acc[ni][0] = fmaf(xhi[ni], whi0, acc[ni][0]);
            acc[ni][1] = fmaf(xlo[ni], wlo1, acc[ni][1]);
            acc[ni][1] = fmaf(xhi[ni], whi1, acc[ni][1]);
        }
    }

    // z = relu(BN(acc)) -> bf16 pairs (kept in regs)
    u32 zp[4];
    #pragma unroll
    for (int ni = 0; ni < 4; ++ni) {
        const float r0 = fmaxf(fmaf(acc[ni][0], A0, C0), 0.0f);
        const float r1 = fmaxf(fmaf(acc[ni][1], A1, C1), 0.0f);
        zp[ni] = f2bfb(r0) | (f2bfb(r1) << 16);
    }
    const float B0 = b_out[j0], B1 = b_out[j0 + 1];
    __syncthreads();                          // all GEMM1 reads of xs/wb done

    // z -> xs, wb <- w_out
    #pragma unroll
    for (int ni = 0; ni < 4; ++ni)
        *(u32*)&xs[(nt * 4 + ni) * XSTU + j0] = zp[ni];
    for (int i = tid; i < Hh * Hh / 8; i += 192)
        ((uint4*)wb)[i] = ((const uint4*)wbg2)[i];
    __syncthreads();

    // ---- GEMM2 (K = 96) ----
    float acc2[4][2] = {};
    #pragma unroll 4
    for (int k2 = 0; k2 < Hh / 2; ++k2) {
        float xlo[4], xhi[4];
        #pragma unroll
        for (int ni = 0; ni < 4; ++ni) {
            const u32 xv = *(const u32*)&xs[(nt * 4 + ni) * XSTU + 2 * k2];
            xlo[ni] = bfL(xv); xhi[ni] = bfH(xv);
        }
        const uint2 wv = *(const uint2*)&((const u32*)wb)[k2 * 96 + j0];
        const float wlo0 = bfL(wv.x), whi0 = bfH(wv.x);
        const float wlo1 = bfL(wv.y), whi1 = bfH(wv.y);
        #pragma unroll
        for (int ni = 0; ni < 4; ++ni) {
            acc2[ni][0] = fmaf(xlo[ni], wlo0, acc2[ni][0]);
            acc2[ni][0] = fmaf(xhi[ni], whi0, acc2[ni][0]);
            acc2[ni][1] = fmaf(xlo[ni], wlo1, acc2[ni][1]);
            acc2[ni][1] = fmaf(xhi[ni], whi1, acc2[ni][1]);
        }
    }

    #pragma unroll
    for (int ni = 0; ni < 4; ++ni) {
        const int node = nbase + nt * 4 + ni;
        const float r0 = fmaxf(acc2[ni][0] + B0, 0.0f);
        const float r1 = fmaxf(acc2[ni][1] + B1, 0.0f);
        *(u32*)(out + (long)node * Hh + j0) = f2bfb(r0) | (f2bfb(r1) << 16);
    }
}

// ---------------------------------------------------------------------------
// Chunked pooling over bf16 table (batch sorted; boundary-flush atomics)
// ---------------------------------------------------------------------------
constexpr int PCHUNK = 64;
__global__ void pool_kernel(const u16* __restrict__ h, const int* __restrict__ batch,
                            float* __restrict__ pooled) {
    const int j = threadIdx.x;                 // 0..95
    const int c0 = blockIdx.x * PCHUNK;
    const int c1 = min(c0 + PCHUNK, Nn);
    if (c0 >= Nn) return;

    int bcur = batch[c0];
    float acc = 0.0f;
    for (int n = c0; n < c1; ++n) {
        const int bb = batch[n];
        if (bb != bcur) {
            atomicAdd(&pooled[(long)bcur * Hh + j], acc);
            acc = 0.0f;
            bcur = bb;
        }
        acc += bf2f(h[(long)n * Hh + j]);
    }
    atomicAdd(&pooled[(long)bcur * Hh + j], acc);
}

// ---------------------------------------------------------------------------
// Head: out[b] = dot(pooled[b], head_w[rt[b]]) + head_b[rt[b]]
// ---------------------------------------------------------------------------
__global__ void head_kernel(const float* __restrict__ pooled, const int* __restrict__ rt,
                            const float* __restrict__ hw, const float* __restrict__ hb,
                            float* __restrict__ outv) {
    const int b = blockIdx.x;
    const int lane = threadIdx.x;
    const int t = rt[b];
    const float* pp = pooled + (long)b * Hh;
    const float* wp = hw + (long)t * Hh;
    float s = 0.0f;
    for (int j = lane; j < Hh; j += 64) s += pp[j] * wp[j];
    #pragma unroll
    for (int off = 32; off > 0; off >>= 1) s += __shfl_down(s, off, 64);
    if (lane == 0) outv[b] = s + hb[t];
}

// ---------------------------------------------------------------------------
extern "C" void kernel_launch(void* const* d_in, const int* in_sizes, int n_in,
                              void* d_out, int out_size, void* d_ws, size_t ws_size,
                              hipStream_t stream) {
    const float* x     = (const float*)d_in[0];
    const int*   ei    = (const int*)d_in[1];      // [2, E] flattened int32
    const int*   src   = ei;
    const int*   dst   = ei + Ee;
    const int*   batch = (const int*)d_in[2];
    const int*   rt    = (const int*)d_in[3];

    const float* P[3][8];
    for (int l = 0; l < 3; ++l)
        for (int p = 0; p < 8; ++p)
            P[l][p] = (const float*)d_in[4 + l * 8 + p];
    const float* head_w = (const float*)d_in[28];
    const float* head_b = (const float*)d_in[29];

    // Workspace layout
    const size_t NH = (size_t)Nn * Hh;
    u16*   tA      = (u16*)d_ws;                       // N*H bf16
    u16*   tB      = tA + NH;                          // N*H bf16
    u16*   xb      = tB + NH;                          // N*INF bf16
    u16*   wball   = xb + (size_t)Nn * INF;            // WB_TOT u16
    float* pooled  = (float*)(wball + WB_TOT);         // B*H fp32
    int*   rowptr  = (int*)(pooled + (size_t)Bb * Hh); // N+1 ints
    int*   counts  = rowptr + Nn + 1;                  // NBIN*P1B ints
    int*   binbase = counts + NBIN * P1B;              // NBIN ints
    u16*   csr     = (u16*)(binbase + NBIN);           // E u16
    // binbuf (12.8 MB) overlays tA+tB (19.2 MB) — both dead during CSR build
    u32*   binbuf  = (u32*)tA;
    float* out     = (float*)d_out;

    const dim3 blk256(256), blk192(192), blk96(96);
    const int GRID_L    = Nn / 16;                     // 3125 (exact)
    const int GRID_POOL = (Nn + PCHUNK - 1) / PCHUNK;

    // ----- precompute tables ; build CSR -----
    x2bf_kernel<<<782, blk256, 0, stream>>>(x, xb);
    w2bf_kernel<<<(WB_TOT / 2 + 255) / 256, blk256, 0, stream>>>(
        P[0][0], P[0][6], P[1][0], P[1][6], P[2][0], P[2][6], wball);
    p1_bin_kernel<<<P1B, blk256, 0, stream>>>(src, dst, binbuf, counts);
    p2_binscan_kernel<<<1, blk256, 0, stream>>>(counts, binbase, rowptr);
    p3_binsort_kernel<<<NBIN, blk256, 0, stream>>>(binbuf, counts, binbase, rowptr, csr);

    // ----- Layer 1: xb -> tA -----
    layer_kernel<INF><<<GRID_L, blk192, 0, stream>>>(xb, rowptr, csr,
        wball + W1I_OFF, wball + W1O_OFF,
        P[0][1], P[0][2], P[0][3], P[0][4], P[0][5], P[0][7], tA);

    // ----- Layer 2: tA -> tB -----
    layer_kernel<Hh><<<GRID_L, blk192, 0, stream>>>(tA, rowptr, csr,
        wball + W2I_OFF, wball + W2O_OFF,
        P[1][1], P[1][2], P[1][3], P[1][4], P[1][5], P[1][7], tB);

    // ----- Layer 3: tB -> tA -----
    layer_kernel<Hh><<<GRID_L, blk192, 0, stream>>>(tB, rowptr, csr,
        wball + W3I_OFF, wball + W3O_OFF,
        P[2][1], P[2][2], P[2][3], P[2][4], P[2][5], P[2][7], tA);

    // ----- Pool (chunked) + head -----
    hipMemsetAsync(pooled, 0, (size_t)Bb * Hh * sizeof(float), stream);
    pool_kernel<<<GRID_POOL, blk96, 0, stream>>>(tA, batch, pooled);
    head_kernel<<<Bb, 64, 0, stream>>>(pooled, rt, head_w, head_b, out);
}